// Round 1
// baseline (5840.668 us; speedup 1.0000x reference)
//
#include <hip/hip_runtime.h>

#define NN 100000
#define NE 1600000
// DIN=64, DH=DOUT=128

// ---------------- degree / dinv ----------------
__global__ void k_deg_init(float* deg) {
    int i = blockIdx.x * blockDim.x + threadIdx.x;
    if (i < NN) deg[i] = 1.0f;  // self-loop
}

__global__ void k_deg_count(const int* __restrict__ dst, float* deg) {
    int i = blockIdx.x * blockDim.x + threadIdx.x;
    if (i < NE) atomicAdd(&deg[dst[i]], 1.0f);
}

__global__ void k_rsqrt(float* deg) {
    int i = blockIdx.x * blockDim.x + threadIdx.x;
    if (i < NN) deg[i] = rsqrtf(deg[i]);
}

// ---------------- GEMM: out[i][j] = sum_k in[i][k] * W[k][j], 128 cols ------
// one row per block, 128 threads. Safe in-place (out==in) for K==128:
// the row is staged to LDS and barriered before any write.
template<int K>
__global__ void k_gemm(const float* __restrict__ in, const float* __restrict__ W,
                       float* __restrict__ out) {
    __shared__ float row[K];
    const int i = blockIdx.x;
    const int j = threadIdx.x;
    if (j < K) row[j] = in[(long long)i * K + j];
    __syncthreads();
    float acc = 0.f;
#pragma unroll 16
    for (int k = 0; k < K; ++k) acc += row[k] * W[k * 128 + j];
    out[(long long)i * 128 + j] = acc;
}

// ---------------- aggregation init: out = b + hw * dinv^2 (self loop) -------
__global__ void k_agg_init(const float* __restrict__ hw, const float* __restrict__ dinv,
                           const float* __restrict__ b, float* __restrict__ out) {
    const int i = blockIdx.x;
    const int j = threadIdx.x;
    float w = dinv[i];
    w = w * w;
    out[(long long)i * 128 + j] = b[j] + hw[(long long)i * 128 + j] * w;
}

// ---------------- edge scatter: out[dst] += hw[src] * dinv[src]*dinv[dst] ---
// 32 threads per edge, 4 floats per thread (float4 gather, 4 scalar atomics)
__global__ void k_scatter(const int* __restrict__ src, const int* __restrict__ dst,
                          const float* __restrict__ dinv, const float* __restrict__ hw,
                          float* __restrict__ out) {
    const unsigned t = blockIdx.x * blockDim.x + threadIdx.x;
    const unsigned e = t >> 5;
    if (e >= NE) return;
    const int c4 = (t & 31) * 4;
    const int s = src[e], d = dst[e];
    const float w = dinv[s] * dinv[d];
    const float4 v = *reinterpret_cast<const float4*>(&hw[(long long)s * 128 + c4]);
    float* o = &out[(long long)d * 128 + c4];
    atomicAdd(o + 0, v.x * w);
    atomicAdd(o + 1, v.y * w);
    atomicAdd(o + 2, v.z * w);
    atomicAdd(o + 3, v.w * w);
}

// ---------------- LayerNorm (eps=1e-5) + ReLU, one wave per row -------------
__global__ void k_ln_relu(const float* __restrict__ in, const float* __restrict__ g,
                          const float* __restrict__ bt, float* __restrict__ out) {
    const int i = blockIdx.x;
    const int l = threadIdx.x;  // 64 lanes
    const float a = in[(long long)i * 128 + l];
    const float b = in[(long long)i * 128 + l + 64];
    float s = a + b;
    float s2 = a * a + b * b;
#pragma unroll
    for (int off = 32; off > 0; off >>= 1) {
        s += __shfl_xor(s, off);
        s2 += __shfl_xor(s2, off);
    }
    const float mu = s * (1.0f / 128.0f);
    const float var = s2 * (1.0f / 128.0f) - mu * mu;
    const float r = rsqrtf(var + 1e-5f);
    const float y0 = (a - mu) * r * g[l] + bt[l];
    const float y1 = (b - mu) * r * g[l + 64] + bt[l + 64];
    out[(long long)i * 128 + l] = fmaxf(y0, 0.f);
    out[(long long)i * 128 + l + 64] = fmaxf(y1, 0.f);
}

extern "C" void kernel_launch(void* const* d_in, const int* in_sizes, int n_in,
                              void* d_out, int out_size, void* d_ws, size_t ws_size,
                              hipStream_t stream) {
    const float* x   = (const float*)d_in[0];
    const int*   ei  = (const int*)d_in[1];
    const float* W1  = (const float*)d_in[2];
    const float* b1  = (const float*)d_in[3];
    const float* g1  = (const float*)d_in[4];
    const float* bt1 = (const float*)d_in[5];
    const float* W2  = (const float*)d_in[6];
    const float* b2  = (const float*)d_in[7];
    const float* g2  = (const float*)d_in[8];
    const float* bt2 = (const float*)d_in[9];

    const int* src = ei;
    const int* dst = ei + NE;

    float* out = (float*)d_out;

    // workspace layout: dinv (N floats, padded) | A (N x 128 floats)
    float* dinv = (float*)d_ws;
    float* A = dinv + ((NN + 255) & ~255);

    // degrees -> dinv
    k_deg_init<<<(NN + 255) / 256, 256, 0, stream>>>(dinv);
    k_deg_count<<<(NE + 255) / 256, 256, 0, stream>>>(dst, dinv);
    k_rsqrt<<<(NN + 255) / 256, 256, 0, stream>>>(dinv);

    const int scatter_blocks = (NE * 32 + 255) / 256;

    // ---- layer 1 ----
    k_gemm<64><<<NN, 128, 0, stream>>>(x, W1, A);           // A = x @ W1
    k_agg_init<<<NN, 128, 0, stream>>>(A, dinv, b1, out);   // out = b1 + self
    k_scatter<<<scatter_blocks, 256, 0, stream>>>(src, dst, dinv, A, out);
    k_ln_relu<<<NN, 64, 0, stream>>>(out, g1, bt1, A);      // A = h1

    // ---- layer 2 ----
    k_gemm<128><<<NN, 128, 0, stream>>>(A, W2, A);          // A = h1 @ W2 (in-place)
    k_agg_init<<<NN, 128, 0, stream>>>(A, dinv, b2, out);
    k_scatter<<<scatter_blocks, 256, 0, stream>>>(src, dst, dinv, A, out);
    k_ln_relu<<<NN, 64, 0, stream>>>(out, g2, bt2, out);    // in-place LN+ReLU
}

// Round 2
// 978.977 us; speedup vs baseline: 5.9661x; 5.9661x over previous
//
#include <hip/hip_runtime.h>

#define NN 100000
#define NE 1600000
// DIN=64, DH=DOUT=128

// ---------------- degree count (int, excludes self-loop; added later) -------
__global__ void k_count(const int* __restrict__ dst, int* __restrict__ cnt) {
    int i = blockIdx.x * blockDim.x + threadIdx.x;
    if (i < NE) atomicAdd(&cnt[dst[i]], 1);
}

__global__ void k_dinv(const int* __restrict__ cnt, float* __restrict__ dinv) {
    int i = blockIdx.x * blockDim.x + threadIdx.x;
    if (i < NN) dinv[i] = rsqrtf(1.0f + (float)cnt[i]);  // +1 self-loop
}

// ---------------- exclusive scan of cnt -> off (single block, 1024 thr) -----
__global__ void k_scan(const int* __restrict__ cnt, int* __restrict__ off) {
    __shared__ int ts[1024];
    const int t = threadIdx.x;
    const int CH = (NN + 1023) / 1024;  // 98
    const int lo = t * CH;
    const int hi = min(lo + CH, NN);
    int s = 0;
    for (int i = lo; i < hi; ++i) s += cnt[i];
    ts[t] = s;
    __syncthreads();
    // inclusive Hillis-Steele scan over thread sums
    for (int d = 1; d < 1024; d <<= 1) {
        int v = (t >= d) ? ts[t - d] : 0;
        __syncthreads();
        ts[t] += v;
        __syncthreads();
    }
    int base = (t == 0) ? 0 : ts[t - 1];
    for (int i = lo; i < hi; ++i) { off[i] = base; base += cnt[i]; }
    if (t == 1023) off[NN] = ts[1023];
}

// ---------------- fill CSR: csr_src[off[d] + pos] = src (pos via atomicSub) -
__global__ void k_fill(const int* __restrict__ src, const int* __restrict__ dst,
                       const int* __restrict__ off, int* __restrict__ cnt,
                       int* __restrict__ csr_src) {
    int e = blockIdx.x * blockDim.x + threadIdx.x;
    if (e >= NE) return;
    const int d = dst[e];
    const int pos = atomicSub(&cnt[d], 1) - 1;
    csr_src[off[d] + pos] = src[e];
}

// ---------------- GEMM: out[i][j] = sum_k in[i][k] * W[k][j], 128 cols ------
template<int K>
__global__ void k_gemm(const float* __restrict__ in, const float* __restrict__ W,
                       float* __restrict__ out) {
    __shared__ float row[K];
    const int i = blockIdx.x;
    const int j = threadIdx.x;
    if (j < K) row[j] = in[(long long)i * K + j];
    __syncthreads();
    float acc = 0.f;
#pragma unroll 16
    for (int k = 0; k < K; ++k) acc += row[k] * W[k * 128 + j];
    out[(long long)i * 128 + j] = acc;
}

// ---------------- fused: CSR gather-sum + bias + LayerNorm + ReLU -----------
// one wave (64 lanes) per node; each lane owns cols {2l, 2l+1}
__global__ void k_agg_ln(const float* __restrict__ A, const int* __restrict__ off,
                         const int* __restrict__ csr_src, const float* __restrict__ dinv,
                         const float* __restrict__ b, const float* __restrict__ g,
                         const float* __restrict__ bt, float* __restrict__ out) {
    const int node = blockIdx.x * (blockDim.x >> 6) + (threadIdx.x >> 6);
    if (node >= NN) return;
    const int lane = threadIdx.x & 63;
    const int c = lane * 2;

    const float di = dinv[node];
    float2 v = *reinterpret_cast<const float2*>(&A[(long long)node * 128 + c]);
    float ax = v.x * (di * di);
    float ay = v.y * (di * di);

    const int e0 = off[node], e1 = off[node + 1];
    for (int e = e0; e < e1; ++e) {
        const int s = csr_src[e];           // wave-uniform -> broadcast
        const float w = dinv[s] * di;
        float2 u = *reinterpret_cast<const float2*>(&A[(long long)s * 128 + c]);
        ax += u.x * w;
        ay += u.y * w;
    }
    ax += b[c];
    ay += b[c + 1];

    // LayerNorm over 128 via wave reduce
    float s1 = ax + ay, s2 = ax * ax + ay * ay;
#pragma unroll
    for (int o = 32; o > 0; o >>= 1) {
        s1 += __shfl_xor(s1, o);
        s2 += __shfl_xor(s2, o);
    }
    const float mu = s1 * (1.0f / 128.0f);
    const float var = s2 * (1.0f / 128.0f) - mu * mu;
    const float r = rsqrtf(var + 1e-5f);
    float y0 = (ax - mu) * r * g[c] + bt[c];
    float y1 = (ay - mu) * r * g[c + 1] + bt[c + 1];
    float2 o2;
    o2.x = fmaxf(y0, 0.f);
    o2.y = fmaxf(y1, 0.f);
    *reinterpret_cast<float2*>(&out[(long long)node * 128 + c]) = o2;
}

extern "C" void kernel_launch(void* const* d_in, const int* in_sizes, int n_in,
                              void* d_out, int out_size, void* d_ws, size_t ws_size,
                              hipStream_t stream) {
    const float* x   = (const float*)d_in[0];
    const int*   ei  = (const int*)d_in[1];
    const float* W1  = (const float*)d_in[2];
    const float* b1  = (const float*)d_in[3];
    const float* g1  = (const float*)d_in[4];
    const float* bt1 = (const float*)d_in[5];
    const float* W2  = (const float*)d_in[6];
    const float* b2  = (const float*)d_in[7];
    const float* g2  = (const float*)d_in[8];
    const float* bt2 = (const float*)d_in[9];

    const int* src = ei;
    const int* dst = ei + NE;

    float* out = (float*)d_out;

    // workspace layout (4B units), each region padded to 256 elems
    const int NP = (NN + 256 + 255) & ~255;  // 100352, covers NN+1
    int*   cnt     = (int*)d_ws;
    int*   off     = cnt + NP;
    float* dinv    = (float*)(off + NP);
    int*   csr_src = (int*)(dinv + NP);
    float* A       = (float*)(csr_src + NE);
    // total: 3*100352 + 1.6M + 12.8M elems ~= 58.8 MB

    // ---- build CSR (shared by both layers) ----
    hipMemsetAsync(cnt, 0, NN * sizeof(int), stream);
    k_count<<<(NE + 255) / 256, 256, 0, stream>>>(dst, cnt);
    k_dinv<<<(NN + 255) / 256, 256, 0, stream>>>(cnt, dinv);
    k_scan<<<1, 1024, 0, stream>>>(cnt, off);
    k_fill<<<(NE + 255) / 256, 256, 0, stream>>>(src, dst, off, cnt, csr_src);

    // ---- layer 1 ----
    k_gemm<64><<<NN, 128, 0, stream>>>(x, W1, A);                 // A = x @ W1
    k_agg_ln<<<(NN + 3) / 4, 256, 0, stream>>>(A, off, csr_src, dinv,
                                               b1, g1, bt1, out);  // out = h1 (temp)

    // ---- layer 2 ----
    k_gemm<128><<<NN, 128, 0, stream>>>(out, W2, A);              // A = h1 @ W2
    k_agg_ln<<<(NN + 3) / 4, 256, 0, stream>>>(A, off, csr_src, dinv,
                                               b2, g2, bt2, out);  // final
}

// Round 3
// 796.721 us; speedup vs baseline: 7.3309x; 1.2288x over previous
//
#include <hip/hip_runtime.h>

#define NN 100000
#define NE 1600000
// DIN=64, DH=DOUT=128

// ---------------- degree count (int, excludes self-loop; added later) -------
__global__ void k_count(const int* __restrict__ dst, int* __restrict__ cnt) {
    int i = blockIdx.x * blockDim.x + threadIdx.x;
    if (i < NE) atomicAdd(&cnt[dst[i]], 1);
}

__global__ void k_dinv(const int* __restrict__ cnt, float* __restrict__ dinv) {
    int i = blockIdx.x * blockDim.x + threadIdx.x;
    if (i < NN) dinv[i] = rsqrtf(1.0f + (float)cnt[i]);  // +1 self-loop
}

// ---------------- exclusive scan of cnt -> off (single block, 1024 thr) -----
__global__ void k_scan(const int* __restrict__ cnt, int* __restrict__ off) {
    __shared__ int ts[1024];
    const int t = threadIdx.x;
    const int CH = (NN + 1023) / 1024;  // 98
    const int lo = t * CH;
    const int hi = min(lo + CH, NN);
    int s = 0;
    for (int i = lo; i < hi; ++i) s += cnt[i];
    ts[t] = s;
    __syncthreads();
    for (int d = 1; d < 1024; d <<= 1) {
        int v = (t >= d) ? ts[t - d] : 0;
        __syncthreads();
        ts[t] += v;
        __syncthreads();
    }
    int base = (t == 0) ? 0 : ts[t - 1];
    for (int i = lo; i < hi; ++i) { off[i] = base; base += cnt[i]; }
    if (t == 1023) off[NN] = ts[1023];
}

// ---------------- fill CSR: csr_src[off[d] + pos] = src -------------------
__global__ void k_fill(const int* __restrict__ src, const int* __restrict__ dst,
                       const int* __restrict__ off, int* __restrict__ cnt,
                       int* __restrict__ csr_src) {
    int e = blockIdx.x * blockDim.x + threadIdx.x;
    if (e >= NE) return;
    const int d = dst[e];
    const int pos = atomicSub(&cnt[d], 1) - 1;
    csr_src[off[d] + pos] = src[e];
}

// ---------------- tiled GEMM: out[NNx128] = in[NNxK] @ W[Kx128] -------------
// 256 threads, 32 rows x 128 cols per block; thread computes 4 rows x 4 cols.
// W (K*128) and x-tile (32*K) staged in LDS. NN % 32 == 0 (100000 = 3125*32).
template<int K>
__global__ __launch_bounds__(256) void k_gemm(const float* __restrict__ in,
                                              const float* __restrict__ W,
                                              float* __restrict__ out) {
    __shared__ float sW[K * 128];
    __shared__ float sX[32 * K];
    const int tid = threadIdx.x;
    const long long row0 = (long long)blockIdx.x * 32;

#pragma unroll
    for (int t = 0; t < K * 128 / 1024; ++t) {
        const int idx = (t * 256 + tid) * 4;
        *reinterpret_cast<float4*>(&sW[idx]) =
            *reinterpret_cast<const float4*>(&W[idx]);
    }
#pragma unroll
    for (int t = 0; t < 32 * K / 1024; ++t) {
        const int idx = (t * 256 + tid) * 4;
        *reinterpret_cast<float4*>(&sX[idx]) =
            *reinterpret_cast<const float4*>(&in[row0 * K + idx]);
    }
    __syncthreads();

    const int jc = (tid & 31) * 4;        // col group (covers 128)
    const int ir = (tid >> 5) * 4;        // row group (covers 32)
    float acc[4][4] = {};

#pragma unroll
    for (int k = 0; k < K; k += 2) {
        const float4 w0 = *reinterpret_cast<const float4*>(&sW[k * 128 + jc]);
        const float4 w1 = *reinterpret_cast<const float4*>(&sW[(k + 1) * 128 + jc]);
#pragma unroll
        for (int r = 0; r < 4; ++r) {
            const float2 xv = *reinterpret_cast<const float2*>(&sX[(ir + r) * K + k]);
            acc[r][0] += xv.x * w0.x + xv.y * w1.x;
            acc[r][1] += xv.x * w0.y + xv.y * w1.y;
            acc[r][2] += xv.x * w0.z + xv.y * w1.z;
            acc[r][3] += xv.x * w0.w + xv.y * w1.w;
        }
    }

#pragma unroll
    for (int r = 0; r < 4; ++r) {
        float4 o;
        o.x = acc[r][0]; o.y = acc[r][1]; o.z = acc[r][2]; o.w = acc[r][3];
        *reinterpret_cast<float4*>(&out[(row0 + ir + r) * 128 + jc]) = o;
    }
}

// ---------------- fused: CSR gather-sum + bias + LayerNorm + ReLU -----------
// one wave (64 lanes) per node; each lane owns cols {2l, 2l+1}
__global__ void k_agg_ln(const float* __restrict__ A, const int* __restrict__ off,
                         const int* __restrict__ csr_src, const float* __restrict__ dinv,
                         const float* __restrict__ b, const float* __restrict__ g,
                         const float* __restrict__ bt, float* __restrict__ out) {
    const int node = blockIdx.x * (blockDim.x >> 6) + (threadIdx.x >> 6);
    if (node >= NN) return;
    const int lane = threadIdx.x & 63;
    const int c = lane * 2;

    const float di = dinv[node];
    float2 v = *reinterpret_cast<const float2*>(&A[(long long)node * 128 + c]);
    float ax = v.x * (di * di);
    float ay = v.y * (di * di);

    const int e0 = off[node], e1 = off[node + 1];
    for (int e = e0; e < e1; ++e) {
        const int s = csr_src[e];           // wave-uniform -> broadcast
        const float w = dinv[s] * di;
        float2 u = *reinterpret_cast<const float2*>(&A[(long long)s * 128 + c]);
        ax += u.x * w;
        ay += u.y * w;
    }
    ax += b[c];
    ay += b[c + 1];

    float s1 = ax + ay, s2 = ax * ax + ay * ay;
#pragma unroll
    for (int o = 32; o > 0; o >>= 1) {
        s1 += __shfl_xor(s1, o);
        s2 += __shfl_xor(s2, o);
    }
    const float mu = s1 * (1.0f / 128.0f);
    const float var = s2 * (1.0f / 128.0f) - mu * mu;
    const float r = rsqrtf(var + 1e-5f);
    float y0 = (ax - mu) * r * g[c] + bt[c];
    float y1 = (ay - mu) * r * g[c + 1] + bt[c + 1];
    float2 o2;
    o2.x = fmaxf(y0, 0.f);
    o2.y = fmaxf(y1, 0.f);
    *reinterpret_cast<float2*>(&out[(long long)node * 128 + c]) = o2;
}

extern "C" void kernel_launch(void* const* d_in, const int* in_sizes, int n_in,
                              void* d_out, int out_size, void* d_ws, size_t ws_size,
                              hipStream_t stream) {
    const float* x   = (const float*)d_in[0];
    const int*   ei  = (const int*)d_in[1];
    const float* W1  = (const float*)d_in[2];
    const float* b1  = (const float*)d_in[3];
    const float* g1  = (const float*)d_in[4];
    const float* bt1 = (const float*)d_in[5];
    const float* W2  = (const float*)d_in[6];
    const float* b2  = (const float*)d_in[7];
    const float* g2  = (const float*)d_in[8];
    const float* bt2 = (const float*)d_in[9];

    const int* src = ei;
    const int* dst = ei + NE;

    float* out = (float*)d_out;

    // workspace layout (4B units), each region padded to 256 elems
    const int NP = (NN + 256 + 255) & ~255;  // covers NN+1
    int*   cnt     = (int*)d_ws;
    int*   off     = cnt + NP;
    float* dinv    = (float*)(off + NP);
    int*   csr_src = (int*)(dinv + NP);
    float* A       = (float*)(csr_src + NE);

    // ---- build CSR (shared by both layers) ----
    hipMemsetAsync(cnt, 0, NN * sizeof(int), stream);
    k_count<<<(NE + 255) / 256, 256, 0, stream>>>(dst, cnt);
    k_dinv<<<(NN + 255) / 256, 256, 0, stream>>>(cnt, dinv);
    k_scan<<<1, 1024, 0, stream>>>(cnt, off);
    k_fill<<<(NE + 255) / 256, 256, 0, stream>>>(src, dst, off, cnt, csr_src);

    // ---- layer 1 ----
    k_gemm<64><<<NN / 32, 256, 0, stream>>>(x, W1, A);             // A = x @ W1
    k_agg_ln<<<(NN + 3) / 4, 256, 0, stream>>>(A, off, csr_src, dinv,
                                               b1, g1, bt1, out);  // out = h1 (temp)

    // ---- layer 2 ----
    k_gemm<128><<<NN / 32, 256, 0, stream>>>(out, W2, A);          // A = h1 @ W2
    k_agg_ln<<<(NN + 3) / 4, 256, 0, stream>>>(A, off, csr_src, dinv,
                                               b2, g2, bt2, out);  // final
}

// Round 4
// 613.990 us; speedup vs baseline: 9.5126x; 1.2976x over previous
//
#include <hip/hip_runtime.h>

#define NN 100000
#define NE 1600000
typedef unsigned short u16;
typedef unsigned int u32;

// ---- bf16 helpers (round-to-nearest-even) ----
__device__ __forceinline__ u32 f2bf(float f) {
    u32 u = __float_as_uint(f);
    return (u + 0x7fffu + ((u >> 16) & 1u)) >> 16;
}
__device__ __forceinline__ u32 pack2(float a, float b) {
    return f2bf(a) | (f2bf(b) << 16);
}

// ---------------- degree count (excludes self-loop; added later) ------------
__global__ void k_count(const int* __restrict__ dst, int* __restrict__ cnt) {
    int i = blockIdx.x * blockDim.x + threadIdx.x;
    if (i < NE) atomicAdd(&cnt[dst[i]], 1);
}

__global__ void k_dinv(const int* __restrict__ cnt, float* __restrict__ dinv) {
    int i = blockIdx.x * blockDim.x + threadIdx.x;
    if (i < NN) dinv[i] = rsqrtf(1.0f + (float)cnt[i]);  // +1 self-loop
}

// ---------------- exclusive scan of cnt -> off (single block) ---------------
__global__ void k_scan(const int* __restrict__ cnt, int* __restrict__ off) {
    __shared__ int ts[1024];
    const int t = threadIdx.x;
    const int CH = (NN + 1023) / 1024;
    const int lo = t * CH;
    const int hi = min(lo + CH, NN);
    int s = 0;
    for (int i = lo; i < hi; ++i) s += cnt[i];
    ts[t] = s;
    __syncthreads();
    for (int d = 1; d < 1024; d <<= 1) {
        int v = (t >= d) ? ts[t - d] : 0;
        __syncthreads();
        ts[t] += v;
        __syncthreads();
    }
    int base = (t == 0) ? 0 : ts[t - 1];
    for (int i = lo; i < hi; ++i) { off[i] = base; base += cnt[i]; }
    if (t == 1023) off[NN] = ts[1023];
}

// ---------------- fill CSR ----------------
__global__ void k_fill(const int* __restrict__ src, const int* __restrict__ dst,
                       const int* __restrict__ off, int* __restrict__ cnt,
                       int* __restrict__ csr_src) {
    int e = blockIdx.x * blockDim.x + threadIdx.x;
    if (e >= NE) return;
    const int d = dst[e];
    const int pos = atomicSub(&cnt[d], 1) - 1;
    csr_src[off[d] + pos] = src[e];
}

// ---------------- tiled GEMM: out[NNx128](bf16) = in[NNxK] @ W[Kx128] -------
// 256 threads, 32 rows x 128 cols per block; thread computes 4 rows x 4 cols.
template<int K, bool BF16IN>
__global__ __launch_bounds__(256) void k_gemm(const void* __restrict__ inp,
                                              const float* __restrict__ W,
                                              u16* __restrict__ out) {
    __shared__ float sW[K * 128];
    __shared__ float sX[32 * K];
    const int tid = threadIdx.x;
    const long long row0 = (long long)blockIdx.x * 32;

#pragma unroll
    for (int t = 0; t < K * 128 / 1024; ++t) {
        const int idx = (t * 256 + tid) * 4;
        *reinterpret_cast<float4*>(&sW[idx]) =
            *reinterpret_cast<const float4*>(&W[idx]);
    }
    if constexpr (BF16IN) {
        const u16* inb = (const u16*)inp;
#pragma unroll
        for (int t = 0; t < 32 * K / 2048; ++t) {
            const int idx = (t * 256 + tid) * 8;
            uint4 v = *reinterpret_cast<const uint4*>(&inb[row0 * K + idx]);
            sX[idx + 0] = __uint_as_float(v.x << 16);
            sX[idx + 1] = __uint_as_float(v.x & 0xffff0000u);
            sX[idx + 2] = __uint_as_float(v.y << 16);
            sX[idx + 3] = __uint_as_float(v.y & 0xffff0000u);
            sX[idx + 4] = __uint_as_float(v.z << 16);
            sX[idx + 5] = __uint_as_float(v.z & 0xffff0000u);
            sX[idx + 6] = __uint_as_float(v.w << 16);
            sX[idx + 7] = __uint_as_float(v.w & 0xffff0000u);
        }
    } else {
        const float* inf = (const float*)inp;
#pragma unroll
        for (int t = 0; t < 32 * K / 1024; ++t) {
            const int idx = (t * 256 + tid) * 4;
            *reinterpret_cast<float4*>(&sX[idx]) =
                *reinterpret_cast<const float4*>(&inf[row0 * K + idx]);
        }
    }
    __syncthreads();

    const int jc = (tid & 31) * 4;
    const int ir = (tid >> 5) * 4;
    float acc[4][4] = {};

#pragma unroll
    for (int k = 0; k < K; k += 2) {
        const float4 w0 = *reinterpret_cast<const float4*>(&sW[k * 128 + jc]);
        const float4 w1 = *reinterpret_cast<const float4*>(&sW[(k + 1) * 128 + jc]);
#pragma unroll
        for (int r = 0; r < 4; ++r) {
            const float2 xv = *reinterpret_cast<const float2*>(&sX[(ir + r) * K + k]);
            acc[r][0] += xv.x * w0.x + xv.y * w1.x;
            acc[r][1] += xv.x * w0.y + xv.y * w1.y;
            acc[r][2] += xv.x * w0.z + xv.y * w1.z;
            acc[r][3] += xv.x * w0.w + xv.y * w1.w;
        }
    }

#pragma unroll
    for (int r = 0; r < 4; ++r) {
        uint2 o;
        o.x = pack2(acc[r][0], acc[r][1]);
        o.y = pack2(acc[r][2], acc[r][3]);
        *reinterpret_cast<uint2*>(&out[(row0 + ir + r) * 128 + jc]) = o;
    }
}

// ---------------- fused: CSR gather-sum(bf16) + bias + LayerNorm + ReLU -----
// one wave per node; lane owns cols {2l, 2l+1}. FP32OUT: fp32 d_out, else bf16.
template<bool FP32OUT>
__global__ __launch_bounds__(256) void k_agg_ln(const u16* __restrict__ A,
                                                const int* __restrict__ off,
                                                const int* __restrict__ csr_src,
                                                const float* __restrict__ dinv,
                                                const float* __restrict__ b,
                                                const float* __restrict__ g,
                                                const float* __restrict__ bt,
                                                void* __restrict__ outp) {
    const int node = blockIdx.x * 4 + (threadIdx.x >> 6);
    if (node >= NN) return;
    const int lane = threadIdx.x & 63;
    const int c = lane * 2;
    const char* Ab = (const char*)A;
    const u32 laneoff = lane << 2;

    const float di = dinv[node];
    const u32 us = *(const u32*)(Ab + (((u32)node) << 8) + laneoff);
    const float wself = di * di;
    float ax = __uint_as_float(us << 16) * wself;
    float ay = __uint_as_float(us & 0xffff0000u) * wself;

    const int e0 = off[node], e1 = off[node + 1];
    for (int base = e0; base < e1; base += 64) {
        const int n = min(64, e1 - base);
        const int idx = csr_src[base + ((lane < n) ? lane : (n - 1))];
        const float dv = dinv[idx];
        int j = 0;
        for (; j + 2 <= n; j += 2) {
            const int sA = __builtin_amdgcn_readlane(idx, j);
            const int sB = __builtin_amdgcn_readlane(idx, j + 1);
            const float wA = __uint_as_float(__builtin_amdgcn_readlane(__float_as_uint(dv), j)) * di;
            const float wB = __uint_as_float(__builtin_amdgcn_readlane(__float_as_uint(dv), j + 1)) * di;
            const u32 uA = *(const u32*)(Ab + (((u32)sA) << 8) + laneoff);
            const u32 uB = *(const u32*)(Ab + (((u32)sB) << 8) + laneoff);
            ax += __uint_as_float(uA << 16) * wA + __uint_as_float(uB << 16) * wB;
            ay += __uint_as_float(uA & 0xffff0000u) * wA + __uint_as_float(uB & 0xffff0000u) * wB;
        }
        if (j < n) {
            const int sA = __builtin_amdgcn_readlane(idx, j);
            const float wA = __uint_as_float(__builtin_amdgcn_readlane(__float_as_uint(dv), j)) * di;
            const u32 uA = *(const u32*)(Ab + (((u32)sA) << 8) + laneoff);
            ax += __uint_as_float(uA << 16) * wA;
            ay += __uint_as_float(uA & 0xffff0000u) * wA;
        }
    }

    const float2 bv = *reinterpret_cast<const float2*>(&b[c]);
    ax += bv.x;
    ay += bv.y;

    float s1 = ax + ay, s2 = ax * ax + ay * ay;
#pragma unroll
    for (int o = 32; o > 0; o >>= 1) {
        s1 += __shfl_xor(s1, o);
        s2 += __shfl_xor(s2, o);
    }
    const float mu = s1 * (1.0f / 128.0f);
    const float var = s2 * (1.0f / 128.0f) - mu * mu;
    const float r = rsqrtf(var + 1e-5f);
    const float2 gv = *reinterpret_cast<const float2*>(&g[c]);
    const float2 tv = *reinterpret_cast<const float2*>(&bt[c]);
    const float y0 = fmaxf((ax - mu) * r * gv.x + tv.x, 0.f);
    const float y1 = fmaxf((ay - mu) * r * gv.y + tv.y, 0.f);

    if constexpr (FP32OUT) {
        float2 o2; o2.x = y0; o2.y = y1;
        *reinterpret_cast<float2*>(&((float*)outp)[(long long)node * 128 + c]) = o2;
    } else {
        *(u32*)((char*)outp + (((u32)node) << 8) + laneoff) = pack2(y0, y1);
    }
}

extern "C" void kernel_launch(void* const* d_in, const int* in_sizes, int n_in,
                              void* d_out, int out_size, void* d_ws, size_t ws_size,
                              hipStream_t stream) {
    const float* x   = (const float*)d_in[0];
    const int*   ei  = (const int*)d_in[1];
    const float* W1  = (const float*)d_in[2];
    const float* b1  = (const float*)d_in[3];
    const float* g1  = (const float*)d_in[4];
    const float* bt1 = (const float*)d_in[5];
    const float* W2  = (const float*)d_in[6];
    const float* b2  = (const float*)d_in[7];
    const float* g2  = (const float*)d_in[8];
    const float* bt2 = (const float*)d_in[9];

    const int* src = ei;
    const int* dst = ei + NE;
    float* out = (float*)d_out;

    // workspace layout (4B units)
    const int NP = (NN + 256 + 255) & ~255;  // covers NN+1
    int*   cnt     = (int*)d_ws;
    int*   off     = cnt + NP;
    float* dinv    = (float*)(off + NP);
    int*   csr_src = (int*)(dinv + NP);
    u16*   A       = (u16*)(csr_src + NE);   // NN*128 bf16  (25.6 MB)
    u16*   h1      = A + (long long)NN * 128; // NN*128 bf16 (25.6 MB)

    // ---- build CSR (shared by both layers) ----
    hipMemsetAsync(cnt, 0, NN * sizeof(int), stream);
    k_count<<<(NE + 255) / 256, 256, 0, stream>>>(dst, cnt);
    k_dinv<<<(NN + 255) / 256, 256, 0, stream>>>(cnt, dinv);
    k_scan<<<1, 1024, 0, stream>>>(cnt, off);
    k_fill<<<(NE + 255) / 256, 256, 0, stream>>>(src, dst, off, cnt, csr_src);

    // ---- layer 1 ----
    k_gemm<64, false><<<NN / 32, 256, 0, stream>>>(x, W1, A);
    k_agg_ln<false><<<NN / 4, 256, 0, stream>>>(A, off, csr_src, dinv,
                                                b1, g1, bt1, h1);

    // ---- layer 2 ----
    k_gemm<128, true><<<NN / 32, 256, 0, stream>>>(h1, W2, A);
    k_agg_ln<true><<<NN / 4, 256, 0, stream>>>(A, off, csr_src, dinv,
                                               b2, g2, bt2, out);
}

// Round 5
// 459.046 us; speedup vs baseline: 12.7235x; 1.3375x over previous
//
#include <hip/hip_runtime.h>

#define NN 100000
#define NE 1600000
#define SCAN_CH 512
#define NBLK ((NN + SCAN_CH - 1) / SCAN_CH)  // 196
typedef unsigned short u16;
typedef unsigned int u32;

// ---- bf16 helpers (round-to-nearest-even) ----
__device__ __forceinline__ u32 f2bf(float f) {
    u32 u = __float_as_uint(f);
    return (u + 0x7fffu + ((u >> 16) & 1u)) >> 16;
}
__device__ __forceinline__ u32 pack2(float a, float b) {
    return f2bf(a) | (f2bf(b) << 16);
}

// ---------------- degree count (excludes self-loop; added later) ------------
__global__ void k_count(const int* __restrict__ dst, int* __restrict__ cnt) {
    int i = blockIdx.x * blockDim.x + threadIdx.x;
    if (i < NE) atomicAdd(&cnt[dst[i]], 1);
}

// ---------------- multi-block scan, phase 1: per-block sums -----------------
__global__ __launch_bounds__(256) void k_scan1(const int* __restrict__ cnt,
                                               int* __restrict__ bsum) {
    const int t = threadIdx.x;
    const int i0 = blockIdx.x * SCAN_CH + t * 2;
    const int c0 = (i0 < NN) ? cnt[i0] : 0;
    const int c1 = (i0 + 1 < NN) ? cnt[i0 + 1] : 0;
    int s = c0 + c1;
#pragma unroll
    for (int o = 1; o < 64; o <<= 1) s += __shfl_xor(s, o);
    __shared__ int ws[4];
    if ((t & 63) == 0) ws[t >> 6] = s;
    __syncthreads();
    if (t == 0) bsum[blockIdx.x] = ws[0] + ws[1] + ws[2] + ws[3];
}

// ---------------- phase 2: exclusive scan of 196 block sums (1 block) -------
__global__ __launch_bounds__(256) void k_scan2(const int* __restrict__ bsum,
                                               int* __restrict__ bbase,
                                               int* __restrict__ off) {
    const int t = threadIdx.x;
    const int lane = t & 63, w = t >> 6;
    const int v = (t < NBLK) ? bsum[t] : 0;
    int s = v;
#pragma unroll
    for (int o = 1; o < 64; o <<= 1) {
        const int u = __shfl_up(s, o);
        if (lane >= o) s += u;
    }
    __shared__ int ws[4];
    if (lane == 63) ws[w] = s;
    __syncthreads();
    int add = 0;
    for (int i = 0; i < w; ++i) add += ws[i];
    if (t < NBLK) bbase[t] = s + add - v;  // exclusive
    if (t == 255) off[NN] = NE;            // total degree = E
}

// ---------------- phase 3: per-block exclusive scan + dinv ------------------
__global__ __launch_bounds__(256) void k_scan3(const int* __restrict__ cnt,
                                               const int* __restrict__ bbase,
                                               int* __restrict__ off,
                                               float* __restrict__ dinv) {
    const int t = threadIdx.x;
    const int i0 = blockIdx.x * SCAN_CH + t * 2;
    const int c0 = (i0 < NN) ? cnt[i0] : 0;
    const int c1 = (i0 + 1 < NN) ? cnt[i0 + 1] : 0;
    const int s = c0 + c1;
    const int lane = t & 63, w = t >> 6;
    int incl = s;
#pragma unroll
    for (int o = 1; o < 64; o <<= 1) {
        const int u = __shfl_up(incl, o);
        if (lane >= o) incl += u;
    }
    __shared__ int ws[4];
    if (lane == 63) ws[w] = incl;
    __syncthreads();
    int base = bbase[blockIdx.x] + incl - s;
    for (int i = 0; i < w; ++i) base += ws[i];
    if (i0 < NN) {
        off[i0] = base;
        dinv[i0] = rsqrtf(1.0f + (float)c0);
    }
    if (i0 + 1 < NN) {
        off[i0 + 1] = base + c0;
        dinv[i0 + 1] = rsqrtf(1.0f + (float)c1);
    }
}

// ---------------- fill CSR ----------------
__global__ void k_fill(const int* __restrict__ src, const int* __restrict__ dst,
                       const int* __restrict__ off, int* __restrict__ cnt,
                       int* __restrict__ csr_src) {
    int e = blockIdx.x * blockDim.x + threadIdx.x;
    if (e >= NE) return;
    const int d = dst[e];
    const int pos = atomicSub(&cnt[d], 1) - 1;
    csr_src[off[d] + pos] = src[e];
}

// ---------------- tiled GEMM: out[NNx128](bf16) = in[NNxK] @ W[Kx128] -------
template<int K, bool BF16IN>
__global__ __launch_bounds__(256) void k_gemm(const void* __restrict__ inp,
                                              const float* __restrict__ W,
                                              u16* __restrict__ out) {
    __shared__ float sW[K * 128];
    __shared__ float sX[32 * K];
    const int tid = threadIdx.x;
    const long long row0 = (long long)blockIdx.x * 32;

#pragma unroll
    for (int t = 0; t < K * 128 / 1024; ++t) {
        const int idx = (t * 256 + tid) * 4;
        *reinterpret_cast<float4*>(&sW[idx]) =
            *reinterpret_cast<const float4*>(&W[idx]);
    }
    if constexpr (BF16IN) {
        const u16* inb = (const u16*)inp;
#pragma unroll
        for (int t = 0; t < 32 * K / 2048; ++t) {
            const int idx = (t * 256 + tid) * 8;
            uint4 v = *reinterpret_cast<const uint4*>(&inb[row0 * K + idx]);
            sX[idx + 0] = __uint_as_float(v.x << 16);
            sX[idx + 1] = __uint_as_float(v.x & 0xffff0000u);
            sX[idx + 2] = __uint_as_float(v.y << 16);
            sX[idx + 3] = __uint_as_float(v.y & 0xffff0000u);
            sX[idx + 4] = __uint_as_float(v.z << 16);
            sX[idx + 5] = __uint_as_float(v.z & 0xffff0000u);
            sX[idx + 6] = __uint_as_float(v.w << 16);
            sX[idx + 7] = __uint_as_float(v.w & 0xffff0000u);
        }
    } else {
        const float* inf = (const float*)inp;
#pragma unroll
        for (int t = 0; t < 32 * K / 1024; ++t) {
            const int idx = (t * 256 + tid) * 4;
            *reinterpret_cast<float4*>(&sX[idx]) =
                *reinterpret_cast<const float4*>(&inf[row0 * K + idx]);
        }
    }
    __syncthreads();

    const int jc = (tid & 31) * 4;
    const int ir = (tid >> 5) * 4;
    float acc[4][4] = {};

#pragma unroll
    for (int k = 0; k < K; k += 2) {
        const float4 w0 = *reinterpret_cast<const float4*>(&sW[k * 128 + jc]);
        const float4 w1 = *reinterpret_cast<const float4*>(&sW[(k + 1) * 128 + jc]);
#pragma unroll
        for (int r = 0; r < 4; ++r) {
            const float2 xv = *reinterpret_cast<const float2*>(&sX[(ir + r) * K + k]);
            acc[r][0] += xv.x * w0.x + xv.y * w1.x;
            acc[r][1] += xv.x * w0.y + xv.y * w1.y;
            acc[r][2] += xv.x * w0.z + xv.y * w1.z;
            acc[r][3] += xv.x * w0.w + xv.y * w1.w;
        }
    }

#pragma unroll
    for (int r = 0; r < 4; ++r) {
        uint2 o;
        o.x = pack2(acc[r][0], acc[r][1]);
        o.y = pack2(acc[r][2], acc[r][3]);
        *reinterpret_cast<uint2*>(&out[(row0 + ir + r) * 128 + jc]) = o;
    }
}

// ---------------- fused: CSR gather-sum(bf16) + bias + LayerNorm + ReLU -----
template<bool FP32OUT>
__global__ __launch_bounds__(256) void k_agg_ln(const u16* __restrict__ A,
                                                const int* __restrict__ off,
                                                const int* __restrict__ csr_src,
                                                const float* __restrict__ dinv,
                                                const float* __restrict__ b,
                                                const float* __restrict__ g,
                                                const float* __restrict__ bt,
                                                void* __restrict__ outp) {
    const int node = blockIdx.x * 4 + (threadIdx.x >> 6);
    if (node >= NN) return;
    const int lane = threadIdx.x & 63;
    const int c = lane * 2;
    const char* Ab = (const char*)A;
    const u32 laneoff = lane << 2;

    const float di = dinv[node];
    const u32 us = *(const u32*)(Ab + (((u32)node) << 8) + laneoff);
    const float wself = di * di;
    float ax = __uint_as_float(us << 16) * wself;
    float ay = __uint_as_float(us & 0xffff0000u) * wself;

    const int e0 = off[node], e1 = off[node + 1];
    for (int base = e0; base < e1; base += 64) {
        const int n = min(64, e1 - base);
        const int idx = csr_src[base + ((lane < n) ? lane : (n - 1))];
        const float dv = dinv[idx];
        int j = 0;
        for (; j + 2 <= n; j += 2) {
            const int sA = __builtin_amdgcn_readlane(idx, j);
            const int sB = __builtin_amdgcn_readlane(idx, j + 1);
            const float wA = __uint_as_float(__builtin_amdgcn_readlane(__float_as_uint(dv), j)) * di;
            const float wB = __uint_as_float(__builtin_amdgcn_readlane(__float_as_uint(dv), j + 1)) * di;
            const u32 uA = *(const u32*)(Ab + (((u32)sA) << 8) + laneoff);
            const u32 uB = *(const u32*)(Ab + (((u32)sB) << 8) + laneoff);
            ax += __uint_as_float(uA << 16) * wA + __uint_as_float(uB << 16) * wB;
            ay += __uint_as_float(uA & 0xffff0000u) * wA + __uint_as_float(uB & 0xffff0000u) * wB;
        }
        if (j < n) {
            const int sA = __builtin_amdgcn_readlane(idx, j);
            const float wA = __uint_as_float(__builtin_amdgcn_readlane(__float_as_uint(dv), j)) * di;
            const u32 uA = *(const u32*)(Ab + (((u32)sA) << 8) + laneoff);
            ax += __uint_as_float(uA << 16) * wA;
            ay += __uint_as_float(uA & 0xffff0000u) * wA;
        }
    }

    const float2 bv = *reinterpret_cast<const float2*>(&b[c]);
    ax += bv.x;
    ay += bv.y;

    float s1 = ax + ay, s2 = ax * ax + ay * ay;
#pragma unroll
    for (int o = 32; o > 0; o >>= 1) {
        s1 += __shfl_xor(s1, o);
        s2 += __shfl_xor(s2, o);
    }
    const float mu = s1 * (1.0f / 128.0f);
    const float var = s2 * (1.0f / 128.0f) - mu * mu;
    const float r = rsqrtf(var + 1e-5f);
    const float2 gv = *reinterpret_cast<const float2*>(&g[c]);
    const float2 tv = *reinterpret_cast<const float2*>(&bt[c]);
    const float y0 = fmaxf((ax - mu) * r * gv.x + tv.x, 0.f);
    const float y1 = fmaxf((ay - mu) * r * gv.y + tv.y, 0.f);

    if constexpr (FP32OUT) {
        float2 o2; o2.x = y0; o2.y = y1;
        *reinterpret_cast<float2*>(&((float*)outp)[(long long)node * 128 + c]) = o2;
    } else {
        *(u32*)((char*)outp + (((u32)node) << 8) + laneoff) = pack2(y0, y1);
    }
}

extern "C" void kernel_launch(void* const* d_in, const int* in_sizes, int n_in,
                              void* d_out, int out_size, void* d_ws, size_t ws_size,
                              hipStream_t stream) {
    const float* x   = (const float*)d_in[0];
    const int*   ei  = (const int*)d_in[1];
    const float* W1  = (const float*)d_in[2];
    const float* b1  = (const float*)d_in[3];
    const float* g1  = (const float*)d_in[4];
    const float* bt1 = (const float*)d_in[5];
    const float* W2  = (const float*)d_in[6];
    const float* b2  = (const float*)d_in[7];
    const float* g2  = (const float*)d_in[8];
    const float* bt2 = (const float*)d_in[9];

    const int* src = ei;
    const int* dst = ei + NE;
    float* out = (float*)d_out;

    // workspace layout (4B units)
    const int NP = (NN + 256 + 255) & ~255;  // covers NN+1
    int*   cnt     = (int*)d_ws;
    int*   off     = cnt + NP;
    float* dinv    = (float*)(off + NP);
    int*   bsum    = (int*)(dinv + NP);      // NBLK=196, pad to 256
    int*   bbase   = bsum + 256;
    int*   csr_src = bbase + 256;
    u16*   A       = (u16*)(csr_src + NE);    // NN*128 bf16  (25.6 MB)
    u16*   h1      = A + (long long)NN * 128; // NN*128 bf16  (25.6 MB)

    // ---- build CSR (shared by both layers) ----
    hipMemsetAsync(cnt, 0, NN * sizeof(int), stream);
    k_count<<<(NE + 255) / 256, 256, 0, stream>>>(dst, cnt);
    k_scan1<<<NBLK, 256, 0, stream>>>(cnt, bsum);
    k_scan2<<<1, 256, 0, stream>>>(bsum, bbase, off);
    k_scan3<<<NBLK, 256, 0, stream>>>(cnt, bbase, off, dinv);
    k_fill<<<(NE + 255) / 256, 256, 0, stream>>>(src, dst, off, cnt, csr_src);

    // ---- layer 1 ----
    k_gemm<64, false><<<NN / 32, 256, 0, stream>>>(x, W1, A);
    k_agg_ln<false><<<NN / 4, 256, 0, stream>>>(A, off, csr_src, dinv,
                                                b1, g1, bt1, h1);

    // ---- layer 2 ----
    k_gemm<128, true><<<NN / 32, 256, 0, stream>>>(h1, W2, A);
    k_agg_ln<true><<<NN / 4, 256, 0, stream>>>(A, off, csr_src, dinv,
                                               b2, g2, bt2, out);
}

// Round 6
// 332.048 us; speedup vs baseline: 17.5898x; 1.3825x over previous
//
#include <hip/hip_runtime.h>

#define NN 100000
#define NE 1600000
#define NBKT 196                 // ceil(NN / 512)
#define EPB 8192                 // edges per block in binning passes
#define ABLK ((NE + EPB - 1) / EPB)  // 196
typedef unsigned short u16;
typedef unsigned int u32;

// ---- bf16 helpers (round-to-nearest-even) ----
__device__ __forceinline__ u32 f2bf(float f) {
    u32 u = __float_as_uint(f);
    return (u + 0x7fffu + ((u >> 16) & 1u)) >> 16;
}
__device__ __forceinline__ u32 pack2(float a, float b) {
    return f2bf(a) | (f2bf(b) << 16);
}

// ---------------- pass A1: per-bucket edge counts (bucket = dst >> 9) -------
__global__ __launch_bounds__(256) void kA1_count(const int* __restrict__ dst,
                                                 int* __restrict__ gcnt) {
    __shared__ int bc[NBKT];
    const int tid = threadIdx.x;
    for (int i = tid; i < NBKT; i += 256) bc[i] = 0;
    __syncthreads();
    const int e0 = blockIdx.x * EPB;
#pragma unroll
    for (int i = 0; i < EPB / 256; ++i) {
        const int e = e0 + i * 256 + tid;
        if (e < NE) atomicAdd(&bc[dst[e] >> 9], 1);
    }
    __syncthreads();
    for (int i = tid; i < NBKT; i += 256)
        if (bc[i]) atomicAdd(&gcnt[i], bc[i]);
}

// ---------------- pass A2: exclusive scan of 196 bucket counts --------------
__global__ __launch_bounds__(256) void kA2_scan(const int* __restrict__ gcnt,
                                                int* __restrict__ bbase,
                                                int* __restrict__ bfill,
                                                int* __restrict__ off) {
    const int t = threadIdx.x;
    const int lane = t & 63, w = t >> 6;
    const int v = (t < NBKT) ? gcnt[t] : 0;
    int s = v;
#pragma unroll
    for (int o = 1; o < 64; o <<= 1) {
        const int u = __shfl_up(s, o);
        if (lane >= o) s += u;
    }
    __shared__ int ws[4];
    if (lane == 63) ws[w] = s;
    __syncthreads();
    int add = 0;
    for (int i = 0; i < w; ++i) add += ws[i];
    const int excl = s + add - v;
    if (t < NBKT) { bbase[t] = excl; bfill[t] = excl; }
    if (t == NBKT) bbase[NBKT] = NE;
    if (t == 255) off[NN] = NE;
}

// ---------------- pass A3: bin edges (packed src<<9 | dst&511) --------------
__global__ __launch_bounds__(256) void kA3_bin(const int* __restrict__ src,
                                               const int* __restrict__ dst,
                                               int* __restrict__ bfill,
                                               u32* __restrict__ binned) {
    __shared__ int bc[NBKT];
    __shared__ int cbase[NBKT];
    const int tid = threadIdx.x;
    for (int i = tid; i < NBKT; i += 256) bc[i] = 0;
    __syncthreads();
    const int e0 = blockIdx.x * EPB;
#pragma unroll
    for (int i = 0; i < EPB / 256; ++i) {
        const int e = e0 + i * 256 + tid;
        if (e < NE) atomicAdd(&bc[dst[e] >> 9], 1);
    }
    __syncthreads();
    for (int i = tid; i < NBKT; i += 256)
        cbase[i] = bc[i] ? atomicAdd(&bfill[i], bc[i]) : 0;
    __syncthreads();
    for (int i = tid; i < NBKT; i += 256) bc[i] = 0;  // reuse as cursor
    __syncthreads();
#pragma unroll
    for (int i = 0; i < EPB / 256; ++i) {
        const int e = e0 + i * 256 + tid;
        if (e < NE) {
            const int d = dst[e];
            const int bkt = d >> 9;
            const int p = atomicAdd(&bc[bkt], 1);
            binned[cbase[bkt] + p] = ((u32)src[e] << 9) | (u32)(d & 511);
        }
    }
}

// ---------------- pass B: per-bucket count + scan -> off/dinv, fill csr -----
__global__ __launch_bounds__(256) void kB_fill(const u32* __restrict__ binned,
                                               const int* __restrict__ bbase,
                                               int* __restrict__ off,
                                               float* __restrict__ dinv,
                                               int* __restrict__ csr_src) {
    __shared__ int lcnt[512];
    __shared__ int lpos[512];
    __shared__ int ws[4];
    const int b = blockIdx.x;
    const int tid = threadIdx.x;
    const int e0 = bbase[b], e1 = bbase[b + 1];
    const int node0 = b << 9;
    lcnt[tid] = 0;
    lcnt[tid + 256] = 0;
    __syncthreads();
    for (int e = e0 + tid; e < e1; e += 256)
        atomicAdd(&lcnt[binned[e] & 511], 1);
    __syncthreads();
    const int c0 = lcnt[tid * 2], c1 = lcnt[tid * 2 + 1];
    const int s = c0 + c1;
    const int lane = tid & 63, w = tid >> 6;
    int incl = s;
#pragma unroll
    for (int o = 1; o < 64; o <<= 1) {
        const int u = __shfl_up(incl, o);
        if (lane >= o) incl += u;
    }
    if (lane == 63) ws[w] = incl;
    __syncthreads();
    int base = incl - s;
    for (int i = 0; i < w; ++i) base += ws[i];
    lpos[tid * 2] = base;
    lpos[tid * 2 + 1] = base + c0;
    const int n0 = node0 + tid * 2;
    if (n0 < NN)     { off[n0] = e0 + base;          dinv[n0] = rsqrtf(1.0f + (float)c0); }
    if (n0 + 1 < NN) { off[n0 + 1] = e0 + base + c0; dinv[n0 + 1] = rsqrtf(1.0f + (float)c1); }
    __syncthreads();
    for (int e = e0 + tid; e < e1; e += 256) {
        const u32 u = binned[e];
        const int p = atomicAdd(&lpos[u & 511], 1);
        csr_src[e0 + p] = (int)(u >> 9);
    }
}

// ---------------- tiled GEMM: out[NNx128](bf16) = in[NNxK] @ W[Kx128] -------
template<int K, bool BF16IN>
__global__ __launch_bounds__(256) void k_gemm(const void* __restrict__ inp,
                                              const float* __restrict__ W,
                                              u16* __restrict__ out) {
    __shared__ float sW[K * 128];
    __shared__ float sX[32 * K];
    const int tid = threadIdx.x;
    const long long row0 = (long long)blockIdx.x * 32;

#pragma unroll
    for (int t = 0; t < K * 128 / 1024; ++t) {
        const int idx = (t * 256 + tid) * 4;
        *reinterpret_cast<float4*>(&sW[idx]) =
            *reinterpret_cast<const float4*>(&W[idx]);
    }
    if constexpr (BF16IN) {
        const u16* inb = (const u16*)inp;
#pragma unroll
        for (int t = 0; t < 32 * K / 2048; ++t) {
            const int idx = (t * 256 + tid) * 8;
            uint4 v = *reinterpret_cast<const uint4*>(&inb[row0 * K + idx]);
            sX[idx + 0] = __uint_as_float(v.x << 16);
            sX[idx + 1] = __uint_as_float(v.x & 0xffff0000u);
            sX[idx + 2] = __uint_as_float(v.y << 16);
            sX[idx + 3] = __uint_as_float(v.y & 0xffff0000u);
            sX[idx + 4] = __uint_as_float(v.z << 16);
            sX[idx + 5] = __uint_as_float(v.z & 0xffff0000u);
            sX[idx + 6] = __uint_as_float(v.w << 16);
            sX[idx + 7] = __uint_as_float(v.w & 0xffff0000u);
        }
    } else {
        const float* inf = (const float*)inp;
#pragma unroll
        for (int t = 0; t < 32 * K / 1024; ++t) {
            const int idx = (t * 256 + tid) * 4;
            *reinterpret_cast<float4*>(&sX[idx]) =
                *reinterpret_cast<const float4*>(&inf[row0 * K + idx]);
        }
    }
    __syncthreads();

    const int jc = (tid & 31) * 4;
    const int ir = (tid >> 5) * 4;
    float acc[4][4] = {};

#pragma unroll
    for (int k = 0; k < K; k += 2) {
        const float4 w0 = *reinterpret_cast<const float4*>(&sW[k * 128 + jc]);
        const float4 w1 = *reinterpret_cast<const float4*>(&sW[(k + 1) * 128 + jc]);
#pragma unroll
        for (int r = 0; r < 4; ++r) {
            const float2 xv = *reinterpret_cast<const float2*>(&sX[(ir + r) * K + k]);
            acc[r][0] += xv.x * w0.x + xv.y * w1.x;
            acc[r][1] += xv.x * w0.y + xv.y * w1.y;
            acc[r][2] += xv.x * w0.z + xv.y * w1.z;
            acc[r][3] += xv.x * w0.w + xv.y * w1.w;
        }
    }

#pragma unroll
    for (int r = 0; r < 4; ++r) {
        uint2 o;
        o.x = pack2(acc[r][0], acc[r][1]);
        o.y = pack2(acc[r][2], acc[r][3]);
        *reinterpret_cast<uint2*>(&out[(row0 + ir + r) * 128 + jc]) = o;
    }
}

// ---------------- fused: CSR gather-sum(bf16) + bias + LayerNorm + ReLU -----
template<bool FP32OUT>
__global__ __launch_bounds__(256) void k_agg_ln(const u16* __restrict__ A,
                                                const int* __restrict__ off,
                                                const int* __restrict__ csr_src,
                                                const float* __restrict__ dinv,
                                                const float* __restrict__ b,
                                                const float* __restrict__ g,
                                                const float* __restrict__ bt,
                                                void* __restrict__ outp) {
    const int node = blockIdx.x * 4 + (threadIdx.x >> 6);
    if (node >= NN) return;
    const int lane = threadIdx.x & 63;
    const int c = lane * 2;
    const char* Ab = (const char*)A;
    const u32 laneoff = lane << 2;

    const float di = dinv[node];
    const u32 us = *(const u32*)(Ab + (((u32)node) << 8) + laneoff);
    const float wself = di * di;
    float ax = __uint_as_float(us << 16) * wself;
    float ay = __uint_as_float(us & 0xffff0000u) * wself;

    const int e0 = off[node], e1 = off[node + 1];
    for (int base = e0; base < e1; base += 64) {
        const int n = min(64, e1 - base);
        const int idx = csr_src[base + ((lane < n) ? lane : (n - 1))];
        const float dv = dinv[idx];
        int j = 0;
        for (; j + 2 <= n; j += 2) {
            const int sA = __builtin_amdgcn_readlane(idx, j);
            const int sB = __builtin_amdgcn_readlane(idx, j + 1);
            const float wA = __uint_as_float(__builtin_amdgcn_readlane(__float_as_uint(dv), j)) * di;
            const float wB = __uint_as_float(__builtin_amdgcn_readlane(__float_as_uint(dv), j + 1)) * di;
            const u32 uA = *(const u32*)(Ab + (((u32)sA) << 8) + laneoff);
            const u32 uB = *(const u32*)(Ab + (((u32)sB) << 8) + laneoff);
            ax += __uint_as_float(uA << 16) * wA + __uint_as_float(uB << 16) * wB;
            ay += __uint_as_float(uA & 0xffff0000u) * wA + __uint_as_float(uB & 0xffff0000u) * wB;
        }
        if (j < n) {
            const int sA = __builtin_amdgcn_readlane(idx, j);
            const float wA = __uint_as_float(__builtin_amdgcn_readlane(__float_as_uint(dv), j)) * di;
            const u32 uA = *(const u32*)(Ab + (((u32)sA) << 8) + laneoff);
            ax += __uint_as_float(uA << 16) * wA;
            ay += __uint_as_float(uA & 0xffff0000u) * wA;
        }
    }

    const float2 bv = *reinterpret_cast<const float2*>(&b[c]);
    ax += bv.x;
    ay += bv.y;

    float s1 = ax + ay, s2 = ax * ax + ay * ay;
#pragma unroll
    for (int o = 32; o > 0; o >>= 1) {
        s1 += __shfl_xor(s1, o);
        s2 += __shfl_xor(s2, o);
    }
    const float mu = s1 * (1.0f / 128.0f);
    const float var = s2 * (1.0f / 128.0f) - mu * mu;
    const float r = rsqrtf(var + 1e-5f);
    const float2 gv = *reinterpret_cast<const float2*>(&g[c]);
    const float2 tv = *reinterpret_cast<const float2*>(&bt[c]);
    const float y0 = fmaxf((ax - mu) * r * gv.x + tv.x, 0.f);
    const float y1 = fmaxf((ay - mu) * r * gv.y + tv.y, 0.f);

    if constexpr (FP32OUT) {
        float2 o2; o2.x = y0; o2.y = y1;
        *reinterpret_cast<float2*>(&((float*)outp)[(long long)node * 128 + c]) = o2;
    } else {
        *(u32*)((char*)outp + (((u32)node) << 8) + laneoff) = pack2(y0, y1);
    }
}

extern "C" void kernel_launch(void* const* d_in, const int* in_sizes, int n_in,
                              void* d_out, int out_size, void* d_ws, size_t ws_size,
                              hipStream_t stream) {
    const float* x   = (const float*)d_in[0];
    const int*   ei  = (const int*)d_in[1];
    const float* W1  = (const float*)d_in[2];
    const float* b1  = (const float*)d_in[3];
    const float* g1  = (const float*)d_in[4];
    const float* bt1 = (const float*)d_in[5];
    const float* W2  = (const float*)d_in[6];
    const float* b2  = (const float*)d_in[7];
    const float* g2  = (const float*)d_in[8];
    const float* bt2 = (const float*)d_in[9];

    const int* src = ei;
    const int* dst = ei + NE;
    float* out = (float*)d_out;

    // workspace layout (4B units)
    const int NP = (NN + 256 + 255) & ~255;  // covers NN+1
    int*   gcnt    = (int*)d_ws;              // 256
    int*   bbase   = gcnt + 256;              // 256 (197 used)
    int*   bfill   = bbase + 256;             // 256
    int*   off     = bfill + 256;             // NP
    float* dinv    = (float*)(off + NP);      // NP
    int*   csr_src = (int*)(dinv + NP);       // NE
    u16*   A       = (u16*)(csr_src + NE);    // NN*128 bf16 (25.6 MB)
    u16*   h1      = A + (long long)NN * 128; // NN*128 bf16 (25.6 MB)
    u32*   binned  = (u32*)h1;                // NE u32, aliases h1 (dead before h1 written)

    // ---- build CSR via two-level binned counting sort ----
    hipMemsetAsync(gcnt, 0, NBKT * sizeof(int), stream);
    kA1_count<<<ABLK, 256, 0, stream>>>(dst, gcnt);
    kA2_scan<<<1, 256, 0, stream>>>(gcnt, bbase, bfill, off);
    kA3_bin<<<ABLK, 256, 0, stream>>>(src, dst, bfill, binned);
    kB_fill<<<NBKT, 256, 0, stream>>>(binned, bbase, off, dinv, csr_src);

    // ---- layer 1 ----
    k_gemm<64, false><<<NN / 32, 256, 0, stream>>>(x, W1, A);
    k_agg_ln<false><<<NN / 4, 256, 0, stream>>>(A, off, csr_src, dinv,
                                                b1, g1, bt1, h1);

    // ---- layer 2 ----
    k_gemm<128, true><<<NN / 32, 256, 0, stream>>>(h1, W2, A);
    k_agg_ln<true><<<NN / 4, 256, 0, stream>>>(A, off, csr_src, dinv,
                                               b2, g2, bt2, out);
}